// Round 4
// baseline (181.307 us; speedup 1.0000x reference)
//
#include <hip/hip_runtime.h>
#include <hip/hip_bf16.h>
#include <math.h>

#define L_SEQ 1024
#define BSZ 8
#define EMB 512
#define NH 8
#define DQ 64
#define BH 64          // BSZ*NH
#define NQKV 1536      // 3*NH*DQ

// Q is pre-scaled by 1/8 (emb_dim/n_head ** -0.5) * log2(e) so that
// softmax numerator = exp2(mfma_score) with zero extra VALU per element.
#define SCALE_Q 0.18033688f

typedef __attribute__((ext_vector_type(8))) short short8;   // 8 bf16 = 4 VGPR
typedef __attribute__((ext_vector_type(4))) float f32x4;

#define GPTR(x) ((const __attribute__((address_space(1))) void*)(x))
#define LPTR(x) ((__attribute__((address_space(3))) void*)(x))

__device__ __forceinline__ unsigned short bf16u(float x) {
  __hip_bfloat16 h = __float2bfloat16(x);
  return *(unsigned short*)&h;
}

// ---------------------------------------------------------------------------
// Kernel 0: f32 -> bf16 convert of emb (8192x512) and W (1536x512).
// ---------------------------------------------------------------------------
__global__ __launch_bounds__(256) void to_bf16(
    const float* __restrict__ emb, const float* __restrict__ W,
    unsigned short* __restrict__ embB, unsigned short* __restrict__ WB) {
  const size_t t = (size_t)blockIdx.x * 256 + threadIdx.x;
  size_t base = t * 8;
  const float* src;
  unsigned short* dst;
  size_t off;
  if (base < (size_t)8192 * 512) { src = emb; dst = embB; off = base; }
  else { src = W; dst = WB; off = base - (size_t)8192 * 512; }
  float4 v0 = *(const float4*)&src[off];
  float4 v1 = *(const float4*)&src[off + 4];
  short8 o;
  o[0] = bf16u(v0.x); o[1] = bf16u(v0.y); o[2] = bf16u(v0.z); o[3] = bf16u(v0.w);
  o[4] = bf16u(v1.x); o[5] = bf16u(v1.y); o[6] = bf16u(v1.z); o[7] = bf16u(v1.w);
  *(short8*)&dst[off] = o;
}

// ---------------------------------------------------------------------------
// Kernel A: QKV projection, bf16 MFMA (m97 pattern). Q gets SCALE_Q folded in.
// ---------------------------------------------------------------------------
__global__ __launch_bounds__(256) void qkv_mfma(
    const unsigned short* __restrict__ A,   // embB [8192][512]
    const unsigned short* __restrict__ B,   // WB   [1536][512]
    const float* __restrict__ bias,
    unsigned short* __restrict__ Qb, unsigned short* __restrict__ Kb,
    unsigned short* __restrict__ Vb) {
  __shared__ __align__(16) unsigned short As[128][32];  // 8 KB, unpadded
  __shared__ __align__(16) unsigned short Bs[128][32];  // 8 KB
  const int tid = threadIdx.x;
  const int wave = tid >> 6, lane = tid & 63;
  const int quad = lane >> 4, col = lane & 15;
  const int wr = wave >> 1, wc = wave & 1;
  const int m0 = blockIdx.y * 128, n0 = blockIdx.x * 128;
  const int r16 = lane >> 2, q4 = lane & 3;

  f32x4 acc[4][4] = {};

  for (int kt = 0; kt < EMB; kt += 32) {
    __syncthreads();
#pragma unroll
    for (int c = 0; c < 2; ++c) {
      const int rowA = (c * 4 + wave) * 16;
      __builtin_amdgcn_global_load_lds(
          GPTR(A + (size_t)(m0 + rowA + r16) * EMB + kt + q4 * 8),
          LPTR(&As[rowA][0]), 16, 0, 0);
      __builtin_amdgcn_global_load_lds(
          GPTR(B + (size_t)(n0 + rowA + r16) * EMB + kt + q4 * 8),
          LPTR(&Bs[rowA][0]), 16, 0, 0);
    }
    __syncthreads();
    short8 af[4], bf[4];
#pragma unroll
    for (int i = 0; i < 4; ++i)
      af[i] = *(const short8*)&As[wr * 64 + i * 16 + col][quad * 8];
#pragma unroll
    for (int j = 0; j < 4; ++j)
      bf[j] = *(const short8*)&Bs[wc * 64 + j * 16 + col][quad * 8];
#pragma unroll
    for (int i = 0; i < 4; ++i)
#pragma unroll
      for (int j = 0; j < 4; ++j)
        acc[i][j] =
            __builtin_amdgcn_mfma_f32_16x16x32_bf16(af[i], bf[j], acc[i][j],
                                                    0, 0, 0);
  }

#pragma unroll
  for (int j = 0; j < 4; ++j) {
    const int o = n0 + wc * 64 + j * 16 + col;
    const float bj = bias[o];
    const int h = o / 192;
    const int c2 = o - h * 192;
    const int sel = c2 >> 6, d = c2 & 63;
    unsigned short* dst = (sel == 0) ? Qb : (sel == 1) ? Kb : Vb;
#pragma unroll
    for (int i = 0; i < 4; ++i) {
      const int mrow = m0 + wr * 64 + i * 16 + quad * 4;
#pragma unroll
      for (int r = 0; r < 4; ++r) {
        const int row = mrow + r;
        const int l = row >> 3, bb = row & 7;
        float val = acc[i][j][r] + bj;
        if (sel == 0) val *= SCALE_Q;
        dst[(((size_t)(bb * NH + h)) * L_SEQ + l) * DQ + d] = bf16u(val);
      }
    }
  }
}

// ---------------------------------------------------------------------------
// Kernel B: two-pass MFMA attention-weight-sum, v3.
// Block = (qc, bh): 64 queries. Pass 1: wave w computes Z for rows w*16..+15,
// sweeping all keys; K staged 4 tiles/round (one per wave), shared.
// invz exchanged via 64-float LDS. Pass 2: wave w owns key tiles w*4..w*4+3,
// stages each privately, computes exp2(s)*invz for ALL 64 query rows (4
// row-group fragments), butterfly-reduces, writes its disjoint columns to
// part. Mask (score==0) dropped: measure-zero for continuous random inputs.
// C/D layout: row=quad*4+reg, col=lane&15 (m89-verified).
// ---------------------------------------------------------------------------
__global__ __launch_bounds__(256) void attn_2pass(
    const unsigned short* __restrict__ Qb, const unsigned short* __restrict__ Kb,
    float* __restrict__ part) {
  const int qc = blockIdx.x;   // 16
  const int bh = blockIdx.y;   // 64
  const int tid = threadIdx.x;
  const int wave = tid >> 6, lane = tid & 63;
  const int quad = lane >> 4, col = lane & 15;

  __shared__ __align__(16) unsigned short Ks[4][64][72];  // 36 KB
  __shared__ float Zs[64];

  const unsigned short* kbase = &Kb[(size_t)bh * L_SEQ * DQ];
  const unsigned short* qbase = &Qb[((size_t)bh * L_SEQ + qc * 64) * DQ];

  // pass-1 Q fragments: this wave's 16 rows
  const unsigned short* qp = qbase + (size_t)(wave * 16 + col) * DQ;
  short8 qa0 = *(const short8*)&qp[quad * 8];
  short8 qa1 = *(const short8*)&qp[32 + quad * 8];

  const int sr = lane >> 2;        // staging row (within 16-row group)
  const int so = (lane & 3) * 16;  // staging col offset (shorts)

  float zacc[4] = {0.f, 0.f, 0.f, 0.f};

  // ---------------- PASS 1: Z per query row ----------------
  for (int round = 0; round < 4; ++round) {
    __syncthreads();
    {
      const unsigned short* src = kbase + (size_t)((round * 4 + wave) * 64) * DQ;
#pragma unroll
      for (int u = 0; u < 4; ++u) {
        const int r = u * 16 + sr;
        const unsigned short* s8 = src + (size_t)r * DQ + so;
        *(short8*)&Ks[wave][r][so] = *(const short8*)s8;
        *(short8*)&Ks[wave][r][so + 8] = *(const short8*)(s8 + 8);
      }
    }
    __syncthreads();
#pragma unroll
    for (int t = 0; t < 4; ++t) {
#pragma unroll
      for (int sub = 0; sub < 4; ++sub) {
        const unsigned short* kp = &Ks[t][sub * 16 + col][0];
        short8 kb0 = *(const short8*)&kp[quad * 8];
        short8 kb1 = *(const short8*)&kp[32 + quad * 8];
        f32x4 s = {0.f, 0.f, 0.f, 0.f};
        s = __builtin_amdgcn_mfma_f32_16x16x32_bf16(qa0, kb0, s, 0, 0, 0);
        s = __builtin_amdgcn_mfma_f32_16x16x32_bf16(qa1, kb1, s, 0, 0, 0);
#pragma unroll
        for (int r = 0; r < 4; ++r) zacc[r] += __builtin_amdgcn_exp2f(s[r]);
      }
    }
  }
  // reduce Z across the 16 cols of each quad-row; publish invz
#pragma unroll
  for (int r = 0; r < 4; ++r) {
    float z = zacc[r];
#pragma unroll
    for (int off = 1; off <= 8; off <<= 1) z += __shfl_xor(z, off, 64);
    float iz = __builtin_amdgcn_rcpf(z);
    if (col == r) Zs[wave * 16 + quad * 4 + r] = iz;
  }
  // pass-2 Q fragments: all 64 rows of this block
  short8 qA[4][2];
#pragma unroll
  for (int rg = 0; rg < 4; ++rg) {
    const unsigned short* qp2 = qbase + (size_t)(rg * 16 + col) * DQ;
    qA[rg][0] = *(const short8*)&qp2[quad * 8];
    qA[rg][1] = *(const short8*)&qp2[32 + quad * 8];
  }
  __syncthreads();
  float ivz[16];
#pragma unroll
  for (int rg = 0; rg < 4; ++rg)
#pragma unroll
    for (int r = 0; r < 4; ++r) ivz[rg * 4 + r] = Zs[rg * 16 + quad * 4 + r];

  // ---------------- PASS 2: colsums, wave-private key tiles ----------------
  const size_t pbase = ((size_t)bh * 16 + qc) * 1024;
  for (int stl = 0; stl < 4; ++stl) {
    const int st = wave * 4 + stl;
    __syncthreads();
    {
      const unsigned short* src = kbase + (size_t)(st * 64) * DQ;
#pragma unroll
      for (int u = 0; u < 4; ++u) {
        const int r = u * 16 + sr;
        const unsigned short* s8 = src + (size_t)r * DQ + so;
        *(short8*)&Ks[wave][r][so] = *(const short8*)s8;
        *(short8*)&Ks[wave][r][so + 8] = *(const short8*)(s8 + 8);
      }
    }
    __syncthreads();
    float cval = 0.f;
#pragma unroll
    for (int sub = 0; sub < 4; ++sub) {
      const unsigned short* kp = &Ks[wave][sub * 16 + col][0];
      short8 kb0 = *(const short8*)&kp[quad * 8];
      short8 kb1 = *(const short8*)&kp[32 + quad * 8];
      float partial = 0.f;
#pragma unroll
      for (int rg = 0; rg < 4; ++rg) {
        f32x4 s = {0.f, 0.f, 0.f, 0.f};
        s = __builtin_amdgcn_mfma_f32_16x16x32_bf16(qA[rg][0], kb0, s, 0, 0, 0);
        s = __builtin_amdgcn_mfma_f32_16x16x32_bf16(qA[rg][1], kb1, s, 0, 0, 0);
#pragma unroll
        for (int r = 0; r < 4; ++r)
          partial = fmaf(__builtin_amdgcn_exp2f(s[r]), ivz[rg * 4 + r], partial);
      }
      partial += __shfl_xor(partial, 16, 64);
      partial += __shfl_xor(partial, 32, 64);
      cval = (sub == quad) ? partial : cval;
    }
    part[pbase + st * 64 + lane] = cval;
  }
}

// ---------------------------------------------------------------------------
// Kernel C1: per-(bh, quarter) aw-reduce + partial O[d]. 256 blocks.
// ---------------------------------------------------------------------------
__global__ __launch_bounds__(256) void finalize_a(
    const float* __restrict__ part, const unsigned short* __restrict__ Vb,
    float* __restrict__ part2) {
  const int bh = blockIdx.x >> 2, g = blockIdx.x & 3;
  const int tid = threadIdx.x;
  __shared__ float aw[256];
  __shared__ float red[4][64];
  {
    const int m = g * 256 + tid;
    float a = 0.f;
#pragma unroll
    for (int qc = 0; qc < 16; ++qc)
      a += part[((size_t)bh * 16 + qc) * 1024 + m];
    aw[tid] = a;
  }
  __syncthreads();
  const int d = tid & 63, sub = tid >> 6;
  float acc = 0.f;
#pragma unroll 8
  for (int mm = 0; mm < 64; ++mm) {
    const int m = g * 256 + sub * 64 + mm;
    __hip_bfloat16 v;
    *(unsigned short*)&v = Vb[((size_t)bh * L_SEQ + m) * DQ + d];
    acc = fmaf(aw[sub * 64 + mm], __bfloat162float(v), acc);
  }
  red[sub][d] = acc;
  __syncthreads();
  if (tid < 64)
    part2[((size_t)bh * 4 + g) * 64 + tid] =
        red[0][tid] + red[1][tid] + red[2][tid] + red[3][tid];
}

// ---------------------------------------------------------------------------
// Kernel C2: reduce 4 partials + GroupNorm(d=64). One wave per bh.
// ---------------------------------------------------------------------------
__global__ __launch_bounds__(64) void finalize_b(
    const float* __restrict__ part2, const float* __restrict__ gnw,
    const float* __restrict__ gnb, float* __restrict__ out) {
  const int bh = blockIdx.x;
  const int d = threadIdx.x;
  float v = 0.f;
#pragma unroll
  for (int g = 0; g < 4; ++g) v += part2[((size_t)bh * 4 + g) * 64 + d];
  float s = v;
#pragma unroll
  for (int off = 32; off >= 1; off >>= 1) s += __shfl_xor(s, off, 64);
  float mean = s * (1.f / 64.f);
  float diff = v - mean;
  float sq = diff * diff;
#pragma unroll
  for (int off = 32; off >= 1; off >>= 1) sq += __shfl_xor(sq, off, 64);
  float var = sq * (1.f / 64.f);
  float o = diff * rsqrtf(var + 1e-5f);
  const int b = bh >> 3, h = bh & 7;
  out[(size_t)b * 512 + h * 64 + d] = o * gnw[h] + gnb[h];
}

extern "C" void kernel_launch(void* const* d_in, const int* in_sizes, int n_in,
                              void* d_out, int out_size, void* d_ws,
                              size_t ws_size, hipStream_t stream) {
  (void)in_sizes; (void)n_in; (void)out_size; (void)ws_size;
  const float* emb  = (const float*)d_in[0];
  const float* W    = (const float*)d_in[1];
  const float* bias = (const float*)d_in[2];
  const float* gnw  = (const float*)d_in[3];
  const float* gnb  = (const float*)d_in[4];
  float* out = (float*)d_out;

  char* ws = (char*)d_ws;
  const size_t perQ = (size_t)BH * L_SEQ * DQ;        // 4,194,304 elems
  unsigned short* embB = (unsigned short*)ws;                      // 8 MB
  unsigned short* WB   = (unsigned short*)(ws + 8u * 1024 * 1024); // 1.5 MB
  unsigned short* Qb   = (unsigned short*)(ws + 10u * 1024 * 1024);
  unsigned short* Kb   = Qb + perQ;
  unsigned short* Vb   = Kb + perQ;
  float* part  = (float*)(ws + 34u * 1024 * 1024);    // 4 MB
  float* part2 = (float*)(ws + 38u * 1024 * 1024);    // 64 KB

  to_bf16<<<dim3(2432), 256, 0, stream>>>(emb, W, embB, WB);
  qkv_mfma<<<dim3(NQKV / 128, 8192 / 128), 256, 0, stream>>>(
      embB, WB, bias, Qb, Kb, Vb);
  attn_2pass<<<dim3(16, BH), 256, 0, stream>>>(Qb, Kb, part);
  finalize_a<<<dim3(BH * 4), 256, 0, stream>>>(part, Vb, part2);
  finalize_b<<<dim3(BH), 64, 0, stream>>>(part2, gnw, gnb, out);
}

// Round 5
// 152.739 us; speedup vs baseline: 1.1870x; 1.1870x over previous
//
#include <hip/hip_runtime.h>
#include <hip/hip_bf16.h>
#include <math.h>

#define L_SEQ 1024
#define BSZ 8
#define EMB 512
#define NH 8
#define DQ 64
#define BH 64          // BSZ*NH
#define NQKV 1536      // 3*NH*DQ

// Q is pre-scaled by (emb_dim/n_head)^-0.5 * log2(e) so that
// softmax numerator = exp2(mfma_score) with zero extra VALU per element.
#define SCALE_Q 0.18033688f

typedef __attribute__((ext_vector_type(8))) short short8;   // 8 bf16 = 4 VGPR
typedef __attribute__((ext_vector_type(4))) float f32x4;

#define GPTR(x) ((const __attribute__((address_space(1))) void*)(x))
#define LPTR(x) ((__attribute__((address_space(3))) void*)(x))

__device__ __forceinline__ unsigned short bf16u(float x) {
  __hip_bfloat16 h = __float2bfloat16(x);
  return *(unsigned short*)&h;
}

// ---------------------------------------------------------------------------
// Kernel 0: f32 -> bf16 convert of emb (8192x512) and W (1536x512).
// ---------------------------------------------------------------------------
__global__ __launch_bounds__(256) void to_bf16(
    const float* __restrict__ emb, const float* __restrict__ W,
    unsigned short* __restrict__ embB, unsigned short* __restrict__ WB) {
  const size_t t = (size_t)blockIdx.x * 256 + threadIdx.x;
  size_t base = t * 8;
  const float* src;
  unsigned short* dst;
  size_t off;
  if (base < (size_t)8192 * 512) { src = emb; dst = embB; off = base; }
  else { src = W; dst = WB; off = base - (size_t)8192 * 512; }
  float4 v0 = *(const float4*)&src[off];
  float4 v1 = *(const float4*)&src[off + 4];
  short8 o;
  o[0] = bf16u(v0.x); o[1] = bf16u(v0.y); o[2] = bf16u(v0.z); o[3] = bf16u(v0.w);
  o[4] = bf16u(v1.x); o[5] = bf16u(v1.y); o[6] = bf16u(v1.z); o[7] = bf16u(v1.w);
  *(short8*)&dst[off] = o;
}

// ---------------------------------------------------------------------------
// Kernel A: QKV projection, bf16 MFMA (m97 pattern). Q gets SCALE_Q folded in.
// ---------------------------------------------------------------------------
__global__ __launch_bounds__(256) void qkv_mfma(
    const unsigned short* __restrict__ A,   // embB [8192][512]
    const unsigned short* __restrict__ B,   // WB   [1536][512]
    const float* __restrict__ bias,
    unsigned short* __restrict__ Qb, unsigned short* __restrict__ Kb,
    unsigned short* __restrict__ Vb) {
  __shared__ __align__(16) unsigned short As[128][32];  // 8 KB, unpadded
  __shared__ __align__(16) unsigned short Bs[128][32];  // 8 KB
  const int tid = threadIdx.x;
  const int wave = tid >> 6, lane = tid & 63;
  const int quad = lane >> 4, col = lane & 15;
  const int wr = wave >> 1, wc = wave & 1;
  const int m0 = blockIdx.y * 128, n0 = blockIdx.x * 128;
  const int r16 = lane >> 2, q4 = lane & 3;

  f32x4 acc[4][4] = {};

  for (int kt = 0; kt < EMB; kt += 32) {
    __syncthreads();
#pragma unroll
    for (int c = 0; c < 2; ++c) {
      const int rowA = (c * 4 + wave) * 16;
      __builtin_amdgcn_global_load_lds(
          GPTR(A + (size_t)(m0 + rowA + r16) * EMB + kt + q4 * 8),
          LPTR(&As[rowA][0]), 16, 0, 0);
      __builtin_amdgcn_global_load_lds(
          GPTR(B + (size_t)(n0 + rowA + r16) * EMB + kt + q4 * 8),
          LPTR(&Bs[rowA][0]), 16, 0, 0);
    }
    __syncthreads();
    short8 af[4], bf[4];
#pragma unroll
    for (int i = 0; i < 4; ++i)
      af[i] = *(const short8*)&As[wr * 64 + i * 16 + col][quad * 8];
#pragma unroll
    for (int j = 0; j < 4; ++j)
      bf[j] = *(const short8*)&Bs[wc * 64 + j * 16 + col][quad * 8];
#pragma unroll
    for (int i = 0; i < 4; ++i)
#pragma unroll
      for (int j = 0; j < 4; ++j)
        acc[i][j] =
            __builtin_amdgcn_mfma_f32_16x16x32_bf16(af[i], bf[j], acc[i][j],
                                                    0, 0, 0);
  }

#pragma unroll
  for (int j = 0; j < 4; ++j) {
    const int o = n0 + wc * 64 + j * 16 + col;
    const float bj = bias[o];
    const int h = o / 192;
    const int c2 = o - h * 192;
    const int sel = c2 >> 6, d = c2 & 63;
    unsigned short* dst = (sel == 0) ? Qb : (sel == 1) ? Kb : Vb;
#pragma unroll
    for (int i = 0; i < 4; ++i) {
      const int mrow = m0 + wr * 64 + i * 16 + quad * 4;
#pragma unroll
      for (int r = 0; r < 4; ++r) {
        const int row = mrow + r;
        const int l = row >> 3, bb = row & 7;
        float val = acc[i][j][r] + bj;
        if (sel == 0) val *= SCALE_Q;
        dst[(((size_t)(bb * NH + h)) * L_SEQ + l) * DQ + d] = bf16u(val);
      }
    }
  }
}

// ---------------------------------------------------------------------------
// Kernel B: two-pass MFMA attention-weight-sum, v4 (split-wave).
// Block = (qc, bh): 64 queries x 1024 keys. Wave w owns rowhalf h=w&1
// (32 rows, rg=0,1) x colhalf c=w>>1 (512 keys, 8 tiles of 64).
// Q fragments (qA[2][2], 16 VGPR) loaded ONCE, used by both passes.
// K staged 4 tiles/round (wave w stages slot w = tile (w>>1)*8+2r+(w&1));
// kb fragments read once per sub, reused for 2 row-groups (4 B/elem LDS).
// Pass 1: Z-partials per colhalf -> Zp[2][64] -> invz per wave's rows.
// Pass 2: colsums over wave's 32 rows -> cs2[h][1024] -> summed to part.
// C/D layout: row=quad*4+reg, col=lane&15 (m89-verified).
// ---------------------------------------------------------------------------
__global__ __launch_bounds__(256) void attn_2pass(
    const unsigned short* __restrict__ Qb, const unsigned short* __restrict__ Kb,
    float* __restrict__ part) {
  const int qc = blockIdx.x;   // 16
  const int bh = blockIdx.y;   // 64
  const int tid = threadIdx.x;
  const int wave = tid >> 6, lane = tid & 63;
  const int quad = lane >> 4, col = lane & 15;
  const int h = wave & 1, c = wave >> 1;

  __shared__ __align__(16) unsigned short Ks[4][64][72];  // 36 KB
  __shared__ float Zp[2][64];      // per-colhalf Z partials
  __shared__ float cs2[2][1024];   // per-rowhalf colsum partials, 8 KB

  const unsigned short* kbase = &Kb[(size_t)bh * L_SEQ * DQ];
  const unsigned short* qbase = &Qb[((size_t)bh * L_SEQ + qc * 64) * DQ];

  // Q fragments for this wave's 32 rows (used in BOTH passes)
  short8 qA[2][2];
#pragma unroll
  for (int rg = 0; rg < 2; ++rg) {
    const unsigned short* qp = qbase + (size_t)(h * 32 + rg * 16 + col) * DQ;
    qA[rg][0] = *(const short8*)&qp[quad * 8];
    qA[rg][1] = *(const short8*)&qp[32 + quad * 8];
  }

  const int sr = lane >> 2;        // staging row within 16-row group
  const int so = (lane & 3) * 16;  // staging col offset (shorts)
  const int stageTile = (wave >> 1) * 8 + (wave & 1);  // + 2*r per round

  float zacc[2][4] = {};

  // ---------------- PASS 1: Z partials over this wave's colhalf ----------
#pragma unroll 1
  for (int r = 0; r < 4; ++r) {
    __syncthreads();
    {
      const unsigned short* src =
          kbase + (size_t)((stageTile + 2 * r) * 64) * DQ;
#pragma unroll
      for (int u = 0; u < 4; ++u) {
        const int rr = u * 16 + sr;
        const unsigned short* s8 = src + (size_t)rr * DQ + so;
        *(short8*)&Ks[wave][rr][so] = *(const short8*)s8;
        *(short8*)&Ks[wave][rr][so + 8] = *(const short8*)(s8 + 8);
      }
    }
    __syncthreads();
#pragma unroll
    for (int p = 0; p < 2; ++p) {
#pragma unroll
      for (int sub = 0; sub < 4; ++sub) {
        const unsigned short* kp = &Ks[c * 2 + p][sub * 16 + col][0];
        short8 kb0 = *(const short8*)&kp[quad * 8];
        short8 kb1 = *(const short8*)&kp[32 + quad * 8];
#pragma unroll
        for (int rg = 0; rg < 2; ++rg) {
          f32x4 s = {0.f, 0.f, 0.f, 0.f};
          s = __builtin_amdgcn_mfma_f32_16x16x32_bf16(qA[rg][0], kb0, s, 0, 0, 0);
          s = __builtin_amdgcn_mfma_f32_16x16x32_bf16(qA[rg][1], kb1, s, 0, 0, 0);
#pragma unroll
          for (int j = 0; j < 4; ++j)
            zacc[rg][j] += __builtin_amdgcn_exp2f(s[j]);
        }
      }
    }
  }
  // butterfly over 16 col-lanes; publish Z partial for this colhalf
#pragma unroll
  for (int rg = 0; rg < 2; ++rg)
#pragma unroll
    for (int j = 0; j < 4; ++j) {
      float z = zacc[rg][j];
#pragma unroll
      for (int off = 1; off <= 8; off <<= 1) z += __shfl_xor(z, off, 64);
      if (col == j) Zp[c][h * 32 + rg * 16 + quad * 4 + j] = z;
    }
  __syncthreads();
  float ivz[2][4];
#pragma unroll
  for (int rg = 0; rg < 2; ++rg)
#pragma unroll
    for (int j = 0; j < 4; ++j) {
      const int row = h * 32 + rg * 16 + quad * 4 + j;
      ivz[rg][j] = __builtin_amdgcn_rcpf(Zp[0][row] + Zp[1][row]);
    }

  // ---------------- PASS 2: colsums over this wave's 32 rows -------------
#pragma unroll 1
  for (int r = 0; r < 4; ++r) {
    __syncthreads();
    {
      const unsigned short* src =
          kbase + (size_t)((stageTile + 2 * r) * 64) * DQ;
#pragma unroll
      for (int u = 0; u < 4; ++u) {
        const int rr = u * 16 + sr;
        const unsigned short* s8 = src + (size_t)rr * DQ + so;
        *(short8*)&Ks[wave][rr][so] = *(const short8*)s8;
        *(short8*)&Ks[wave][rr][so + 8] = *(const short8*)(s8 + 8);
      }
    }
    __syncthreads();
#pragma unroll
    for (int p = 0; p < 2; ++p) {
      const int T = c * 8 + 2 * r + p;  // absolute key tile
      float cval = 0.f;
#pragma unroll
      for (int sub = 0; sub < 4; ++sub) {
        const unsigned short* kp = &Ks[c * 2 + p][sub * 16 + col][0];
        short8 kb0 = *(const short8*)&kp[quad * 8];
        short8 kb1 = *(const short8*)&kp[32 + quad * 8];
        float partial = 0.f;
#pragma unroll
        for (int rg = 0; rg < 2; ++rg) {
          f32x4 s = {0.f, 0.f, 0.f, 0.f};
          s = __builtin_amdgcn_mfma_f32_16x16x32_bf16(qA[rg][0], kb0, s, 0, 0, 0);
          s = __builtin_amdgcn_mfma_f32_16x16x32_bf16(qA[rg][1], kb1, s, 0, 0, 0);
#pragma unroll
          for (int j = 0; j < 4; ++j)
            partial = fmaf(__builtin_amdgcn_exp2f(s[j]), ivz[rg][j], partial);
        }
        partial += __shfl_xor(partial, 16, 64);
        partial += __shfl_xor(partial, 32, 64);
        cval = (sub == quad) ? partial : cval;
      }
      cs2[h][T * 64 + lane] = cval;  // column T*64+lane, this rowhalf
    }
  }
  __syncthreads();
  const size_t pbase = ((size_t)bh * 16 + qc) * 1024;
  for (int i = tid; i < 1024; i += 256)
    part[pbase + i] = cs2[0][i] + cs2[1][i];
}

// ---------------------------------------------------------------------------
// Kernel C1: per-(bh, quarter) aw-reduce + partial O[d]. 256 blocks.
// ---------------------------------------------------------------------------
__global__ __launch_bounds__(256) void finalize_a(
    const float* __restrict__ part, const unsigned short* __restrict__ Vb,
    float* __restrict__ part2) {
  const int bh = blockIdx.x >> 2, g = blockIdx.x & 3;
  const int tid = threadIdx.x;
  __shared__ float aw[256];
  __shared__ float red[4][64];
  {
    const int m = g * 256 + tid;
    float a = 0.f;
#pragma unroll
    for (int qc = 0; qc < 16; ++qc)
      a += part[((size_t)bh * 16 + qc) * 1024 + m];
    aw[tid] = a;
  }
  __syncthreads();
  const int d = tid & 63, sub = tid >> 6;
  float acc = 0.f;
#pragma unroll 8
  for (int mm = 0; mm < 64; ++mm) {
    const int m = g * 256 + sub * 64 + mm;
    __hip_bfloat16 v;
    *(unsigned short*)&v = Vb[((size_t)bh * L_SEQ + m) * DQ + d];
    acc = fmaf(aw[sub * 64 + mm], __bfloat162float(v), acc);
  }
  red[sub][d] = acc;
  __syncthreads();
  if (tid < 64)
    part2[((size_t)bh * 4 + g) * 64 + tid] =
        red[0][tid] + red[1][tid] + red[2][tid] + red[3][tid];
}

// ---------------------------------------------------------------------------
// Kernel C2: reduce 4 partials + GroupNorm(d=64). One wave per bh.
// ---------------------------------------------------------------------------
__global__ __launch_bounds__(64) void finalize_b(
    const float* __restrict__ part2, const float* __restrict__ gnw,
    const float* __restrict__ gnb, float* __restrict__ out) {
  const int bh = blockIdx.x;
  const int d = threadIdx.x;
  float v = 0.f;
#pragma unroll
  for (int g = 0; g < 4; ++g) v += part2[((size_t)bh * 4 + g) * 64 + d];
  float s = v;
#pragma unroll
  for (int off = 32; off >= 1; off >>= 1) s += __shfl_xor(s, off, 64);
  float mean = s * (1.f / 64.f);
  float diff = v - mean;
  float sq = diff * diff;
#pragma unroll
  for (int off = 32; off >= 1; off >>= 1) sq += __shfl_xor(sq, off, 64);
  float var = sq * (1.f / 64.f);
  float o = diff * rsqrtf(var + 1e-5f);
  const int b = bh >> 3, h = bh & 7;
  out[(size_t)b * 512 + h * 64 + d] = o * gnw[h] + gnb[h];
}

extern "C" void kernel_launch(void* const* d_in, const int* in_sizes, int n_in,
                              void* d_out, int out_size, void* d_ws,
                              size_t ws_size, hipStream_t stream) {
  (void)in_sizes; (void)n_in; (void)out_size; (void)ws_size;
  const float* emb  = (const float*)d_in[0];
  const float* W    = (const float*)d_in[1];
  const float* bias = (const float*)d_in[2];
  const float* gnw  = (const float*)d_in[3];
  const float* gnb  = (const float*)d_in[4];
  float* out = (float*)d_out;

  char* ws = (char*)d_ws;
  const size_t perQ = (size_t)BH * L_SEQ * DQ;        // 4,194,304 elems
  unsigned short* embB = (unsigned short*)ws;                      // 8 MB
  unsigned short* WB   = (unsigned short*)(ws + 8u * 1024 * 1024); // 1.5 MB
  unsigned short* Qb   = (unsigned short*)(ws + 10u * 1024 * 1024);
  unsigned short* Kb   = Qb + perQ;
  unsigned short* Vb   = Kb + perQ;
  float* part  = (float*)(ws + 34u * 1024 * 1024);    // 4 MB
  float* part2 = (float*)(ws + 38u * 1024 * 1024);    // 64 KB

  to_bf16<<<dim3(2432), 256, 0, stream>>>(emb, W, embB, WB);
  qkv_mfma<<<dim3(NQKV / 128, 8192 / 128), 256, 0, stream>>>(
      embB, WB, bias, Qb, Kb, Vb);
  attn_2pass<<<dim3(16, BH), 256, 0, stream>>>(Qb, Kb, part);
  finalize_a<<<dim3(BH * 4), 256, 0, stream>>>(part, Vb, part2);
  finalize_b<<<dim3(BH), 64, 0, stream>>>(part2, gnw, gnb, out);
}